// Round 5
// baseline (209.082 us; speedup 1.0000x reference)
//
#include <hip/hip_runtime.h>
#include <hip/hip_bf16.h>

// LightningAttention MI355X — round 5: split-bf16 MFMA + register-shuffle transposes.
// No big LDS buffers, no mid-kernel barriers; occupancy up from 2 blocks/CU.
// B=8 T=8192 DM=128 H=8 Dh=16.

typedef __attribute__((ext_vector_type(8))) short short8;   // 8 bf16 (MFMA A/B frag)
typedef __attribute__((ext_vector_type(4))) float floatx4;  // MFMA C/D frag

#define DEV __device__ __forceinline__
#define MFMA __builtin_amdgcn_mfma_f32_16x16x32_bf16

DEV unsigned short bfh(float f) {
  unsigned int x = __float_as_uint(f);
  x += 0x7fffu + ((x >> 16) & 1u);     // RNE
  return (unsigned short)(x >> 16);
}
DEV float bfdec(unsigned short u) { return __uint_as_float(((unsigned int)u) << 16); }
DEV void splitf(float f, unsigned short& h, unsigned short& l) {
  h = bfh(f);
  l = bfh(f - bfdec(h));
}
DEV void split8(const float* p, short8& h8, short8& l8) {
  float4 a = *(const float4*)p;
  float4 b = *(const float4*)(p + 4);
  float v[8] = {a.x, a.y, a.z, a.w, b.x, b.y, b.z, b.w};
  union { short8 s; unsigned short u[8]; } H, L;
#pragma unroll
  for (int i = 0; i < 8; ++i) splitf(v[i], H.u[i], L.u[i]);
  h8 = H.s; l8 = L.s;
}

// Register transpose: from C-layout tile val(n=lane16, m=mt*16+quad*4+r) held as
// floatx4 rows m0 (mt=base) / m1 (mt=base+1), build split A/B-frag
// F[lane16][k=quad*8+j] = val(n=lane16, m=16*base + quad*8 + j)  — m-window of 32.
DEV void xpose_frag(floatx4 m0, floatx4 m1, int lane16, int quad,
                    short8& hi, short8& lo) {
  union { short8 s; unsigned short u[8]; } H, L;
#pragma unroll
  for (int j = 0; j < 8; ++j) {
    int srcLane = lane16 + (((quad & 1) * 2 + (j >> 2)) << 4);
    float vA = __shfl(m0[j & 3], srcLane, 64);
    float vB = __shfl(m1[j & 3], srcLane, 64);
    float v = (quad < 2) ? vA : vB;
    splitf(v, H.u[j], L.u[j]);
  }
  hi = H.s; lo = L.s;
}

// ---------------- k_prep: weight transpose -> split bf16 + zero ctx/ksum ----------------
__global__ void k_prep(const float* __restrict__ Wq, const float* __restrict__ Wk,
                       const float* __restrict__ Wv, const float* __restrict__ Wo,
                       unsigned short* __restrict__ WTh, unsigned short* __restrict__ WTl,
                       float* __restrict__ ctxz) {
  int gid = blockIdx.x * 256 + threadIdx.x;
  if (gid < 8192) {               // 4 mats x 128 n x 16 k-groups of 8
    int mat = gid >> 11, r = gid & 2047, n = r >> 4, k0 = (r & 15) * 8;
    const float* W = (mat == 0) ? Wq : (mat == 1) ? Wk : (mat == 2) ? Wv : Wo;
    union { uint4 q; unsigned short u[8]; } oh, ol;
#pragma unroll
    for (int i = 0; i < 8; ++i) splitf(W[(size_t)(k0 + i) * 128 + n], oh.u[i], ol.u[i]);
    *(uint4*)&WTh[mat * 16384 + n * 128 + k0] = oh.q;
    *(uint4*)&WTl[mat * 16384 + n * 128 + k0] = ol.q;
  } else if (gid < 8192 + 17408) {
    ctxz[gid - 8192] = 0.0f;      // ctx (16384) + ksum (1024)
  }
}

DEV void stage_rope64(int tid, int t0, float rc[64][9], float rs[64][9]) {
#pragma unroll
  for (int p = 0; p < 2; ++p) {
    int idx = tid + p * 256;
    int r = idx >> 3, j = idx & 7;
    float invf = 1.0f / powf(10000.0f, (float)j * 0.125f);
    float s, c;
    sincosf((float)(t0 + r) * invf, &s, &c);
    rc[r][j] = c; rs[r][j] = s;
  }
}

// ---------------- kernel 1: kv GEMM + rope/elu(k) + ctx/ksum (wave-local heads) ----------------
__global__ __launch_bounds__(256) void k_kv_ctx(
    const float* __restrict__ x,
    const unsigned short* __restrict__ WTkh, const unsigned short* __restrict__ WTkl,
    const unsigned short* __restrict__ WTvh, const unsigned short* __restrict__ WTvl,
    const float* __restrict__ bk, const float* __restrict__ bv,
    float* __restrict__ ctx, float* __restrict__ ksum) {
  __shared__ float rc[64][9], rs[64][9];
  const int tid = threadIdx.x;
  const int row0 = blockIdx.x * 64;
  const int b = row0 >> 13;
  const int t0 = row0 & 8191;

  stage_rope64(tid, t0, rc, rs);
  __syncthreads();                 // only barrier in this kernel

  const int l = tid & 63, w = tid >> 6;
  const int lane16 = l & 15, quad = l >> 4;
  // wave w owns heads {2w, 2w+1}: k cols w*32+{0,16}+lane16 (nt 0,1), v cols same (nt 2,3)

  floatx4 acc[4][4];               // [nt][mt]
#pragma unroll
  for (int i = 0; i < 4; ++i)
#pragma unroll
    for (int j = 0; j < 4; ++j) acc[i][j] = (floatx4){0.f, 0.f, 0.f, 0.f};

#pragma unroll
  for (int ks = 0; ks < 4; ++ks) {
    short8 afh[4], afl[4];
#pragma unroll
    for (int mt = 0; mt < 4; ++mt)
      split8(x + (size_t)(row0 + mt * 16 + lane16) * 128 + ks * 32 + quad * 8, afh[mt], afl[mt]);
#pragma unroll
    for (int nt = 0; nt < 4; ++nt) {
      size_t wrow = (size_t)(w * 32 + (nt & 1) * 16 + lane16) * 128 + ks * 32 + quad * 8;
      const unsigned short* ph = (nt < 2) ? WTkh : WTvh;
      const unsigned short* pl = (nt < 2) ? WTkl : WTvl;
      short8 bh = *(const short8*)(ph + wrow);
      short8 bl = *(const short8*)(pl + wrow);
#pragma unroll
      for (int mt = 0; mt < 4; ++mt) {
        acc[nt][mt] = MFMA(afh[mt], bh, acc[nt][mt], 0, 0, 0);
        acc[nt][mt] = MFMA(afl[mt], bh, acc[nt][mt], 0, 0, 0);
        acc[nt][mt] = MFMA(afh[mt], bl, acc[nt][mt], 0, 0, 0);
      }
    }
  }

  // bias (lane = col within tile)
#pragma unroll
  for (int nt = 0; nt < 4; ++nt) {
    int col = w * 32 + (nt & 1) * 16 + lane16;
    float bias = (nt < 2) ? bk[col] : bv[col];
#pragma unroll
    for (int mt = 0; mt < 4; ++mt)
#pragma unroll
      for (int r = 0; r < 4; ++r) acc[nt][mt][r] += bias;
  }

  // rope + elu+1 on k tiles (nt 0,1). lane16 = d within head; t = mt*16+quad*4+r.
  {
    const int d = lane16, j = d & 7;
#pragma unroll
    for (int mt = 0; mt < 4; ++mt) {
      float cc[4], ss[4];
#pragma unroll
      for (int r = 0; r < 4; ++r) {
        int tl = mt * 16 + quad * 4 + r;
        cc[r] = rc[tl][j]; ss[r] = rs[tl][j];
      }
#pragma unroll
      for (int nt = 0; nt < 2; ++nt) {
#pragma unroll
        for (int r = 0; r < 4; ++r) {
          float v = acc[nt][mt][r];
          float p = __shfl_xor(v, 8);          // pair (d, d+8) within head
          float nv = (d < 8) ? (v * cc[r] - p * ss[r]) : (p * ss[r] + v * cc[r]);
          acc[nt][mt][r] = (nv > 0.f) ? (nv + 1.f) : __expf(nv);
        }
      }
    }
  }

  // ksum[h][d] for heads 2w+nt
#pragma unroll
  for (int nt = 0; nt < 2; ++nt) {
    float s = 0.f;
#pragma unroll
    for (int mt = 0; mt < 4; ++mt)
#pragma unroll
      for (int r = 0; r < 4; ++r) s += acc[nt][mt][r];
    s += __shfl_xor(s, 16);
    s += __shfl_xor(s, 32);
    if (l < 16) atomicAdd(&ksum[(b * 8 + w * 2 + nt) * 16 + lane16], s);
  }

  // ctx[h] += K_h^T V_h via register transposes (contraction over t, 2 windows of 32)
#pragma unroll
  for (int hl = 0; hl < 2; ++hl) {
    int h = w * 2 + hl;
    floatx4 c = (floatx4){0.f, 0.f, 0.f, 0.f};
#pragma unroll
    for (int ks2 = 0; ks2 < 2; ++ks2) {
      short8 kh, kl, vh, vl;
      xpose_frag(acc[hl][ks2 * 2], acc[hl][ks2 * 2 + 1], lane16, quad, kh, kl);       // lane16=d
      xpose_frag(acc[2 + hl][ks2 * 2], acc[2 + hl][ks2 * 2 + 1], lane16, quad, vh, vl); // lane16=e
      c = MFMA(kh, vh, c, 0, 0, 0);
      c = MFMA(kl, vh, c, 0, 0, 0);
      c = MFMA(kh, vl, c, 0, 0, 0);
    }
#pragma unroll
    for (int r = 0; r < 4; ++r)
      atomicAdd(&ctx[((size_t)(b * 8 + h) * 16 + quad * 4 + r) * 16 + lane16], c[r]);
  }
}

// ---------------- kernel 2: q^T GEMM + rope/elu + apply + @Wo (barrier-free body) ----------------
__global__ __launch_bounds__(256) void k_q_out(
    const float* __restrict__ x,
    const unsigned short* __restrict__ WTqh, const unsigned short* __restrict__ WTql,
    const unsigned short* __restrict__ WToh, const unsigned short* __restrict__ WTol,
    const float* __restrict__ bq, const float* __restrict__ bo,
    const float* __restrict__ ctx, const float* __restrict__ ksum,
    float* __restrict__ out) {
  __shared__ float rc[64][9], rs[64][9];
  __shared__ unsigned short CTh[8 * 16 * 40], CTl[8 * 16 * 40];  // [h][e][32-window, half zero]
  __shared__ float ksumS[128], bqS[128], boS[128];
  const int tid = threadIdx.x;
  const int row0 = blockIdx.x * 64;
  const int b = row0 >> 13;
  const int t0 = row0 & 8191;

  stage_rope64(tid, t0, rc, rs);
  if (tid < 128) {   // CT[h][e][p*16+d] = ctx[h][d][e], other 16-half zero (p = h&1)
    int h = tid >> 4, e = tid & 15, p = h & 1;
    unsigned int base = (h * 16 + e) * 40;
    union { uint4 q; unsigned int u[4]; } z0; z0.u[0] = z0.u[1] = z0.u[2] = z0.u[3] = 0;
    *(uint4*)&CTh[base + (1 - p) * 16] = z0.q;
    *(uint4*)&CTh[base + (1 - p) * 16 + 8] = z0.q;
    *(uint4*)&CTl[base + (1 - p) * 16] = z0.q;
    *(uint4*)&CTl[base + (1 - p) * 16 + 8] = z0.q;
    const float* cp = ctx + (size_t)(b * 8 + h) * 256 + e;
    union { uint4 q; unsigned short u[8]; } ch, cl;
#pragma unroll
    for (int d = 0; d < 8; ++d) splitf(cp[d * 16], ch.u[d], cl.u[d]);
    *(uint4*)&CTh[base + p * 16] = ch.q;
    *(uint4*)&CTl[base + p * 16] = cl.q;
#pragma unroll
    for (int d = 0; d < 8; ++d) splitf(cp[(8 + d) * 16], ch.u[d], cl.u[d]);
    *(uint4*)&CTh[base + p * 16 + 8] = ch.q;
    *(uint4*)&CTl[base + p * 16 + 8] = cl.q;
  } else {
    int t2 = tid - 128;
    ksumS[t2] = ksum[b * 128 + t2];
    bqS[t2] = bq[t2];
    boS[t2] = bo[t2];
  }
  __syncthreads();                 // only barrier in this kernel

  const int l = tid & 63, w = tid >> 6;
  const int lane16 = l & 15, quad = l >> 4;
  const int trow = row0 + w * 16 + lane16;     // lane = t

  // ---- Phase A: q^T: D[m=qcol][n=t]; A = WTq rows, B = x rows (split) ----
  short8 xbh[4], xbl[4];
#pragma unroll
  for (int ks = 0; ks < 4; ++ks)
    split8(x + (size_t)trow * 128 + ks * 32 + quad * 8, xbh[ks], xbl[ks]);
  floatx4 qacc[8];
#pragma unroll
  for (int i = 0; i < 8; ++i) qacc[i] = (floatx4){0.f, 0.f, 0.f, 0.f};
#pragma unroll
  for (int mt = 0; mt < 8; ++mt) {
#pragma unroll
    for (int ks = 0; ks < 4; ++ks) {
      size_t off = (size_t)(mt * 16 + lane16) * 128 + ks * 32 + quad * 8;
      short8 afh = *(const short8*)(WTqh + off);
      short8 afl = *(const short8*)(WTql + off);
      qacc[mt] = MFMA(afh, xbh[ks], qacc[mt], 0, 0, 0);
      qacc[mt] = MFMA(afl, xbh[ks], qacc[mt], 0, 0, 0);
      qacc[mt] = MFMA(afh, xbl[ks], qacc[mt], 0, 0, 0);
    }
  }

  // ---- Phase B: bias + rope + elu+1 + z; q' back into qacc ----
  float cc[4], ss[4];
#pragma unroll
  for (int r = 0; r < 4; ++r) {                // d = quad*4+r; j = (quad&1)*4+r
    cc[r] = rc[w * 16 + lane16][(quad & 1) * 4 + r];
    ss[r] = rs[w * 16 + lane16][(quad & 1) * 4 + r];
  }
  float zi[8];
#pragma unroll
  for (int h = 0; h < 8; ++h) {
    float qp[4];
#pragma unroll
    for (int r = 0; r < 4; ++r) {
      float v = qacc[h][r] + bqS[h * 16 + quad * 4 + r];
      float p = __shfl_xor(v, 32);             // pair (d, d+8): quad ^ 2
      float nv = (quad < 2) ? (v * cc[r] - p * ss[r]) : (p * ss[r] + v * cc[r]);
      qp[r] = (nv > 0.f) ? (nv + 1.f) : __expf(nv);
    }
    float zp = 0.f;
#pragma unroll
    for (int r = 0; r < 4; ++r) zp += qp[r] * ksumS[h * 16 + quad * 4 + r];
    zp += __shfl_xor(zp, 16);
    zp += __shfl_xor(zp, 32);
    zi[h] = 1.0f / (zp + 1e-6f);
#pragma unroll
    for (int r = 0; r < 4; ++r) qacc[h][r] = qp[r];
  }

  // ---- Phase C: apply. B-frag = q'-window via register transpose; A = CT (LDS). ----
  short8 qwh[4], qwl[4];
#pragma unroll
  for (int hp = 0; hp < 4; ++hp)
    xpose_frag(qacc[hp * 2], qacc[hp * 2 + 1], lane16, quad, qwh[hp], qwl[hp]);
  floatx4 of[8];
#pragma unroll
  for (int h = 0; h < 8; ++h) {
    int ca = (h * 16 + lane16) * 40 + quad * 8;
    short8 avh = *(const short8*)&CTh[ca];
    short8 avl = *(const short8*)&CTl[ca];
    floatx4 o = (floatx4){0.f, 0.f, 0.f, 0.f};
    o = MFMA(avh, qwh[h >> 1], o, 0, 0, 0);
    o = MFMA(avl, qwh[h >> 1], o, 0, 0, 0);
    o = MFMA(avh, qwl[h >> 1], o, 0, 0, 0);
#pragma unroll
    for (int r = 0; r < 4; ++r) of[h][r] = o[r] * zi[h];   // D[m=e][n=t]: lane16 = t
  }

  // ---- Phase D: out = O @ Wo + bo. A-frag = o-window via register transpose. ----
  short8 oah[4], oal[4];
#pragma unroll
  for (int ks = 0; ks < 4; ++ks)
    xpose_frag(of[ks * 2], of[ks * 2 + 1], lane16, quad, oah[ks], oal[ks]);
  floatx4 oacc[8];
#pragma unroll
  for (int i = 0; i < 8; ++i) oacc[i] = (floatx4){0.f, 0.f, 0.f, 0.f};
#pragma unroll
  for (int nt = 0; nt < 8; ++nt) {
#pragma unroll
    for (int ks = 0; ks < 4; ++ks) {
      size_t off = (size_t)(nt * 16 + lane16) * 128 + ks * 32 + quad * 8;
      short8 wbh = *(const short8*)(WToh + off);
      short8 wbl = *(const short8*)(WTol + off);
      oacc[nt] = MFMA(oah[ks], wbh, oacc[nt], 0, 0, 0);
      oacc[nt] = MFMA(oal[ks], wbh, oacc[nt], 0, 0, 0);
      oacc[nt] = MFMA(oah[ks], wbl, oacc[nt], 0, 0, 0);
    }
  }
#pragma unroll
  for (int nt = 0; nt < 8; ++nt) {
    int oc = nt * 16 + lane16;
    float bb = boS[oc];
#pragma unroll
    for (int r = 0; r < 4; ++r) {
      int t = row0 + w * 16 + quad * 4 + r;
      out[(size_t)t * 128 + oc] = oacc[nt][r] + bb;
    }
  }
}

extern "C" void kernel_launch(void* const* d_in, const int* in_sizes, int n_in,
                              void* d_out, int out_size, void* d_ws, size_t ws_size,
                              hipStream_t stream) {
  const float* x  = (const float*)d_in[0];
  const float* Wq = (const float*)d_in[1];
  const float* bq = (const float*)d_in[2];
  const float* Wk = (const float*)d_in[3];
  const float* bk = (const float*)d_in[4];
  const float* Wv = (const float*)d_in[5];
  const float* bv = (const float*)d_in[6];
  const float* Wo = (const float*)d_in[7];
  const float* bo = (const float*)d_in[8];
  float* out = (float*)d_out;

  unsigned short* WTh = (unsigned short*)d_ws;         // 4 x 16384 bf16 hi = 128 KB
  unsigned short* WTl = WTh + 65536;                   // 4 x 16384 bf16 lo = 128 KB
  float* ctx  = (float*)((char*)d_ws + 262144);        // 16384 f
  float* ksum = ctx + 16384;                           // 1024 f   (total ws ~326 KB)

  k_prep<<<100, 256, 0, stream>>>(Wq, Wk, Wv, Wo, WTh, WTl, ctx);
  k_kv_ctx<<<1024, 256, 0, stream>>>(x, WTh + 16384, WTl + 16384, WTh + 32768, WTl + 32768,
                                     bk, bv, ctx, ksum);
  k_q_out<<<1024, 256, 0, stream>>>(x, WTh, WTl, WTh + 49152, WTl + 49152,
                                    bq, bo, ctx, ksum, out);
}

// Round 6
// 172.338 us; speedup vs baseline: 1.2132x; 1.2132x over previous
//
#include <hip/hip_runtime.h>
#include <hip/hip_bf16.h>

// LightningAttention MI355X — round 6: fused qkv kernel (x read once, 288 MFMA/wave),
// q' -> ws (bf16), kernel2 = apply + Wo only (32 rows/wave, Wo frags reused 2x).
// Split-bf16 (hi+lo) everywhere except q' surface. B=8 T=8192 DM=128 H=8 Dh=16.

typedef __attribute__((ext_vector_type(8))) short short8;   // 8 bf16 (MFMA A/B frag)
typedef __attribute__((ext_vector_type(4))) float floatx4;  // MFMA C/D frag

#define DEV __device__ __forceinline__
#define MFMA __builtin_amdgcn_mfma_f32_16x16x32_bf16

DEV unsigned short bfh(float f) {
  unsigned int x = __float_as_uint(f);
  x += 0x7fffu + ((x >> 16) & 1u);     // RNE
  return (unsigned short)(x >> 16);
}
DEV float bfdec(unsigned short u) { return __uint_as_float(((unsigned int)u) << 16); }
DEV void splitf(float f, unsigned short& h, unsigned short& l) {
  h = bfh(f);
  l = bfh(f - bfdec(h));
}
DEV void split8(const float* p, short8& h8, short8& l8) {
  float4 a = *(const float4*)p;
  float4 b = *(const float4*)(p + 4);
  float v[8] = {a.x, a.y, a.z, a.w, b.x, b.y, b.z, b.w};
  union { short8 s; unsigned short u[8]; } H, L;
#pragma unroll
  for (int i = 0; i < 8; ++i) splitf(v[i], H.u[i], L.u[i]);
  h8 = H.s; l8 = L.s;
}

// Register transpose: C-layout tile val(n=lane16, m=mt*16+quad*4+r) rows m0/m1 ->
// split frag F[lane16][k=quad*8+j] over the 32-wide m-window. (Verified R5.)
DEV void xpose_frag(floatx4 m0, floatx4 m1, int lane16, int quad,
                    short8& hi, short8& lo) {
  union { short8 s; unsigned short u[8]; } H, L;
#pragma unroll
  for (int j = 0; j < 8; ++j) {
    int srcLane = lane16 + (((quad & 1) * 2 + (j >> 2)) << 4);
    float vA = __shfl(m0[j & 3], srcLane, 64);
    float vB = __shfl(m1[j & 3], srcLane, 64);
    float v = (quad < 2) ? vA : vB;
    splitf(v, H.u[j], L.u[j]);
  }
  hi = H.s; lo = L.s;
}

// ---------------- k_prep: weight transpose -> split bf16 + zero ctx/ksum ----------------
__global__ void k_prep(const float* __restrict__ Wq, const float* __restrict__ Wk,
                       const float* __restrict__ Wv, const float* __restrict__ Wo,
                       unsigned short* __restrict__ WTh, unsigned short* __restrict__ WTl,
                       float* __restrict__ ctxz) {
  int gid = blockIdx.x * 256 + threadIdx.x;
  if (gid < 8192) {               // 4 mats x 128 n x 16 k-groups of 8
    int mat = gid >> 11, r = gid & 2047, n = r >> 4, k0 = (r & 15) * 8;
    const float* W = (mat == 0) ? Wq : (mat == 1) ? Wk : (mat == 2) ? Wv : Wo;
    union { uint4 q; unsigned short u[8]; } oh, ol;
#pragma unroll
    for (int i = 0; i < 8; ++i) splitf(W[(size_t)(k0 + i) * 128 + n], oh.u[i], ol.u[i]);
    *(uint4*)&WTh[mat * 16384 + n * 128 + k0] = oh.q;
    *(uint4*)&WTl[mat * 16384 + n * 128 + k0] = ol.q;
  } else if (gid < 8192 + 17408) {
    ctxz[gid - 8192] = 0.0f;      // ctx (16384) + ksum (1024)
  }
}

DEV void stage_rope64(int tid, int t0, float rc[64][9], float rs[64][9]) {
#pragma unroll
  for (int p = 0; p < 2; ++p) {
    int idx = tid + p * 256;
    int r = idx >> 3, j = idx & 7;
    float invf = 1.0f / powf(10000.0f, (float)j * 0.125f);
    float s, c;
    sincosf((float)(t0 + r) * invf, &s, &c);
    rc[r][j] = c; rs[r][j] = s;
  }
}

// ---------------- kernel 1: qkv GEMM + rope/elu(q,k) + q'->ws + ctx/ksum ----------------
// Wave w owns heads {2w, 2w+1}: nt 0,1 = q; 2,3 = k; 4,5 = v (16 cols each).
__global__ __launch_bounds__(256, 2) void k_qkv_ctx(
    const float* __restrict__ x,
    const unsigned short* __restrict__ WTh, const unsigned short* __restrict__ WTl,
    const float* __restrict__ bq, const float* __restrict__ bk, const float* __restrict__ bv,
    float* __restrict__ ctx, float* __restrict__ ksum,
    unsigned short* __restrict__ qws) {
  __shared__ float rc[64][9], rs[64][9];
  const int tid = threadIdx.x;
  const int row0 = blockIdx.x * 64;
  const int b = row0 >> 13;
  const int t0 = row0 & 8191;

  stage_rope64(tid, t0, rc, rs);
  __syncthreads();                 // only barrier

  const int l = tid & 63, w = tid >> 6;
  const int lane16 = l & 15, quad = l >> 4;

  floatx4 acc[6][4];               // [nt][mt]
#pragma unroll
  for (int i = 0; i < 6; ++i)
#pragma unroll
    for (int j = 0; j < 4; ++j) acc[i][j] = (floatx4){0.f, 0.f, 0.f, 0.f};

#pragma unroll
  for (int ks = 0; ks < 4; ++ks) {
    short8 afh[4], afl[4];
#pragma unroll
    for (int mt = 0; mt < 4; ++mt)
      split8(x + (size_t)(row0 + mt * 16 + lane16) * 128 + ks * 32 + quad * 8, afh[mt], afl[mt]);
#pragma unroll
    for (int nt = 0; nt < 6; ++nt) {
      int mat = nt >> 1;           // 0=Wq 1=Wk 2=Wv (matches WT packing order)
      size_t woff = (size_t)mat * 16384 +
                    (size_t)(w * 32 + (nt & 1) * 16 + lane16) * 128 + ks * 32 + quad * 8;
      short8 bh = *(const short8*)(WTh + woff);
      short8 bl = *(const short8*)(WTl + woff);
#pragma unroll
      for (int mt = 0; mt < 4; ++mt) {
        acc[nt][mt] = MFMA(afh[mt], bh, acc[nt][mt], 0, 0, 0);
        acc[nt][mt] = MFMA(afl[mt], bh, acc[nt][mt], 0, 0, 0);
        acc[nt][mt] = MFMA(afh[mt], bl, acc[nt][mt], 0, 0, 0);
      }
    }
  }

  // bias (lane = col within tile)
#pragma unroll
  for (int nt = 0; nt < 6; ++nt) {
    int col = w * 32 + (nt & 1) * 16 + lane16;
    int mat = nt >> 1;
    float bias = (mat == 0) ? bq[col] : (mat == 1) ? bk[col] : bv[col];
#pragma unroll
    for (int mt = 0; mt < 4; ++mt)
#pragma unroll
      for (int r = 0; r < 4; ++r) acc[nt][mt][r] += bias;
  }

  // rope + elu+1 on q and k tiles (nt 0..3). lane16 = d within head.
  {
    const int d = lane16, j = d & 7;
#pragma unroll
    for (int mt = 0; mt < 4; ++mt) {
      float cc[4], ss[4];
#pragma unroll
      for (int r = 0; r < 4; ++r) {
        int tl = mt * 16 + quad * 4 + r;
        cc[r] = rc[tl][j]; ss[r] = rs[tl][j];
      }
#pragma unroll
      for (int nt = 0; nt < 4; ++nt) {
#pragma unroll
        for (int r = 0; r < 4; ++r) {
          float v = acc[nt][mt][r];
          float p = __shfl_xor(v, 8);          // pair (d, d+8)
          float nv = (d < 8) ? (v * cc[r] - p * ss[r]) : (p * ss[r] + v * cc[r]);
          acc[nt][mt][r] = (nv > 0.f) ? (nv + 1.f) : __expf(nv);
        }
      }
    }
  }

  // ksum from k tiles (nt 2,3)
#pragma unroll
  for (int kt = 0; kt < 2; ++kt) {
    float s = 0.f;
#pragma unroll
    for (int mt = 0; mt < 4; ++mt)
#pragma unroll
      for (int r = 0; r < 4; ++r) s += acc[2 + kt][mt][r];
    s += __shfl_xor(s, 16);
    s += __shfl_xor(s, 32);
    if (l < 16) atomicAdd(&ksum[(b * 8 + w * 2 + kt) * 16 + lane16], s);
  }

  // q' -> ws as bf16 [t][128] (nt 0,1)
#pragma unroll
  for (int qt = 0; qt < 2; ++qt) {
    int h = w * 2 + qt;
#pragma unroll
    for (int mt = 0; mt < 4; ++mt)
#pragma unroll
      for (int r = 0; r < 4; ++r)
        qws[(size_t)(row0 + mt * 16 + quad * 4 + r) * 128 + h * 16 + lane16] =
            bfh(acc[qt][mt][r]);
  }

  // ctx[h] += K_h^T V_h via register transposes (k = nt 2,3; v = nt 4,5)
#pragma unroll
  for (int hl = 0; hl < 2; ++hl) {
    int h = w * 2 + hl;
    floatx4 c = (floatx4){0.f, 0.f, 0.f, 0.f};
#pragma unroll
    for (int ks2 = 0; ks2 < 2; ++ks2) {
      short8 kh, kl, vh, vl;
      xpose_frag(acc[2 + hl][ks2 * 2], acc[2 + hl][ks2 * 2 + 1], lane16, quad, kh, kl);
      xpose_frag(acc[4 + hl][ks2 * 2], acc[4 + hl][ks2 * 2 + 1], lane16, quad, vh, vl);
      c = MFMA(kh, vh, c, 0, 0, 0);
      c = MFMA(kl, vh, c, 0, 0, 0);
      c = MFMA(kh, vl, c, 0, 0, 0);
    }
#pragma unroll
    for (int r = 0; r < 4; ++r)
      atomicAdd(&ctx[((size_t)(b * 8 + h) * 16 + quad * 4 + r) * 16 + lane16], c[r]);
  }
}

// ---------------- kernel 2: apply (q'C)*z + @Wo. 128 rows/block, 32 rows/wave ----------------
__global__ __launch_bounds__(256, 2) void k_apply_out(
    const unsigned short* __restrict__ qws,
    const unsigned short* __restrict__ WToh, const unsigned short* __restrict__ WTol,
    const float* __restrict__ bo,
    const float* __restrict__ ctx, const float* __restrict__ ksum,
    float* __restrict__ out) {
  __shared__ unsigned short CTh[8 * 16 * 40], CTl[8 * 16 * 40];  // [h][e][32-window, half zero]
  __shared__ float ksumS[128], boS[128];
  const int tid = threadIdx.x;
  const int row0 = blockIdx.x * 128;
  const int b = row0 >> 13;

  if (tid < 128) {   // CT[h][e][p*16+d] = ctx[h][d][e], other 16-half zero (p = h&1)
    int h = tid >> 4, e = tid & 15, p = h & 1;
    unsigned int base = (h * 16 + e) * 40;
    union { uint4 q; unsigned int u[4]; } z0; z0.u[0] = z0.u[1] = z0.u[2] = z0.u[3] = 0;
    *(uint4*)&CTh[base + (1 - p) * 16] = z0.q;
    *(uint4*)&CTh[base + (1 - p) * 16 + 8] = z0.q;
    *(uint4*)&CTl[base + (1 - p) * 16] = z0.q;
    *(uint4*)&CTl[base + (1 - p) * 16 + 8] = z0.q;
    const float* cp = ctx + (size_t)(b * 8 + h) * 256 + e;
    union { uint4 q; unsigned short u[8]; } ch, cl;
#pragma unroll
    for (int d = 0; d < 8; ++d) splitf(cp[d * 16], ch.u[d], cl.u[d]);
    *(uint4*)&CTh[base + p * 16] = ch.q;
    *(uint4*)&CTl[base + p * 16] = cl.q;
#pragma unroll
    for (int d = 0; d < 8; ++d) splitf(cp[(8 + d) * 16], ch.u[d], cl.u[d]);
    *(uint4*)&CTh[base + p * 16 + 8] = ch.q;
    *(uint4*)&CTl[base + p * 16 + 8] = cl.q;
  } else {
    int t2 = tid - 128;
    ksumS[t2] = ksum[b * 128 + t2];
    boS[t2] = bo[t2];
  }
  __syncthreads();                 // only barrier

  const int l = tid & 63, w = tid >> 6;
  const int lane16 = l & 15, quad = l >> 4;

  floatx4 of[2][8];
  short8 qf[2][4];
  float ziP[2][4];

#pragma unroll
  for (int mt2 = 0; mt2 < 2; ++mt2) {
    int trow = row0 + w * 32 + mt2 * 16 + lane16;   // lane = t
    // q' B-frags: [lane16=t][k = quad*8+j over head-pair window hp]
#pragma unroll
    for (int hp = 0; hp < 4; ++hp)
      qf[mt2][hp] = *(const short8*)&qws[(size_t)trow * 128 + hp * 32 + quad * 8];
    // z per (t, head): per-lane partial over this quad's 8 d's -> pair-sum over quad LSB
#pragma unroll
    for (int hp = 0; hp < 4; ++hp) {
      union { short8 s8; unsigned short u[8]; } qq; qq.s8 = qf[mt2][hp];
      float s = 0.f;
#pragma unroll
      for (int jj = 0; jj < 8; ++jj)
        s += bfdec(qq.u[jj]) * ksumS[hp * 32 + quad * 8 + jj];
      s += __shfl_xor(s, 16);       // quads {0,1}: head even sum; {2,3}: head odd
      ziP[mt2][hp] = 1.0f / (s + 1e-6f);
    }
    // apply: D2[m=e][n=t] = CT_h @ q'frag; scale by z
#pragma unroll
    for (int h = 0; h < 8; ++h) {
      int ca = (h * 16 + lane16) * 40 + quad * 8;
      short8 avh = *(const short8*)&CTh[ca];
      short8 avl = *(const short8*)&CTl[ca];
      floatx4 o = (floatx4){0.f, 0.f, 0.f, 0.f};
      o = MFMA(avh, qf[mt2][h >> 1], o, 0, 0, 0);
      o = MFMA(avl, qf[mt2][h >> 1], o, 0, 0, 0);
      float zz = __shfl(ziP[mt2][h >> 1], ((h & 1) << 5) + lane16, 64);
#pragma unroll
      for (int r = 0; r < 4; ++r) of[mt2][h][r] = o[r] * zz;
    }
  }

  // Phase D: out = O @ Wo + bo. A-frags from of via register transpose.
  short8 oah[2][4], oal[2][4];
#pragma unroll
  for (int mt2 = 0; mt2 < 2; ++mt2)
#pragma unroll
    for (int ksx = 0; ksx < 4; ++ksx)
      xpose_frag(of[mt2][ksx * 2], of[mt2][ksx * 2 + 1], lane16, quad, oah[mt2][ksx], oal[mt2][ksx]);

  floatx4 oacc[2][8];
#pragma unroll
  for (int i = 0; i < 2; ++i)
#pragma unroll
    for (int j = 0; j < 8; ++j) oacc[i][j] = (floatx4){0.f, 0.f, 0.f, 0.f};

#pragma unroll
  for (int nt = 0; nt < 8; ++nt) {
#pragma unroll
    for (int ks = 0; ks < 4; ++ks) {
      size_t off = (size_t)(nt * 16 + lane16) * 128 + ks * 32 + quad * 8;
      short8 wbh = *(const short8*)(WToh + off);
      short8 wbl = *(const short8*)(WTol + off);
#pragma unroll
      for (int mt2 = 0; mt2 < 2; ++mt2) {
        oacc[mt2][nt] = MFMA(oah[mt2][ks], wbh, oacc[mt2][nt], 0, 0, 0);
        oacc[mt2][nt] = MFMA(oal[mt2][ks], wbh, oacc[mt2][nt], 0, 0, 0);
        oacc[mt2][nt] = MFMA(oah[mt2][ks], wbl, oacc[mt2][nt], 0, 0, 0);
      }
    }
  }

#pragma unroll
  for (int nt = 0; nt < 8; ++nt) {
    int oc = nt * 16 + lane16;
    float bb = boS[oc];
#pragma unroll
    for (int mt2 = 0; mt2 < 2; ++mt2)
#pragma unroll
      for (int r = 0; r < 4; ++r) {
        int t = row0 + w * 32 + mt2 * 16 + quad * 4 + r;
        out[(size_t)t * 128 + oc] = oacc[mt2][nt][r] + bb;
      }
  }
}

extern "C" void kernel_launch(void* const* d_in, const int* in_sizes, int n_in,
                              void* d_out, int out_size, void* d_ws, size_t ws_size,
                              hipStream_t stream) {
  const float* x  = (const float*)d_in[0];
  const float* Wq = (const float*)d_in[1];
  const float* bq = (const float*)d_in[2];
  const float* Wk = (const float*)d_in[3];
  const float* bk = (const float*)d_in[4];
  const float* Wv = (const float*)d_in[5];
  const float* bv = (const float*)d_in[6];
  const float* Wo = (const float*)d_in[7];
  const float* bo = (const float*)d_in[8];
  float* out = (float*)d_out;

  // ws layout: qws (16.78 MB) | WTh (128 KB) | WTl (128 KB) | ctx (64 KB) | ksum (4 KB)
  unsigned short* qws = (unsigned short*)d_ws;         // 65536*128 shorts
  unsigned short* WTh = qws + 8388608;                 // 4 x 16384
  unsigned short* WTl = WTh + 65536;
  float* ctx  = (float*)(WTl + 65536);                 // 16384 f
  float* ksum = ctx + 16384;                           // 1024 f (contiguous after ctx)

  k_prep<<<100, 256, 0, stream>>>(Wq, Wk, Wv, Wo, WTh, WTl, ctx);
  k_qkv_ctx<<<1024, 256, 0, stream>>>(x, WTh, WTl, bq, bk, bv, ctx, ksum, qws);
  k_apply_out<<<512, 256, 0, stream>>>(qws, WTh + 3 * 16384, WTl + 3 * 16384,
                                       bo, ctx, ksum, out);
}

// Round 7
// 171.649 us; speedup vs baseline: 1.2181x; 1.0040x over previous
//
#include <hip/hip_runtime.h>
#include <hip/hip_bf16.h>

// LightningAttention MI355X — round 7.
// k_prep:  split-transpose Wq/Wk/Wv -> ws; zero ctx/ksum.
// k_qkv:   8 waves/block, wave = 1 head. x staged pre-split in LDS (split once).
//          qkv GEMM -> rope/elu+1(q,k) -> q'->ws bf16, ksum, ctx atomics.
// k_mprep: M_h = C_h @ Wo_h (fp32), stacked M^T split-bf16 -> ws.   [out = (z.q')@M + bo]
// k_zout:  one GEMM: load q' (A-frag layout direct), compute z in-reg, scale+split, @M.
// B=8 T=8192 DM=128 H=8 Dh=16. Split-bf16 (hi+lo) on all MFMA surfaces except q' (bf16).

typedef __attribute__((ext_vector_type(8))) short short8;   // 8 bf16 (MFMA A/B frag)
typedef __attribute__((ext_vector_type(4))) float floatx4;  // MFMA C/D frag

#define DEV __device__ __forceinline__
#define MFMA __builtin_amdgcn_mfma_f32_16x16x32_bf16

DEV unsigned short bfh(float f) {
  unsigned int x = __float_as_uint(f);
  x += 0x7fffu + ((x >> 16) & 1u);     // RNE
  return (unsigned short)(x >> 16);
}
DEV float bfdec(unsigned short u) { return __uint_as_float(((unsigned int)u) << 16); }
DEV void splitf(float f, unsigned short& h, unsigned short& l) {
  h = bfh(f);
  l = bfh(f - bfdec(h));
}
DEV void split8(const float* p, short8& h8, short8& l8) {
  float4 a = *(const float4*)p;
  float4 b = *(const float4*)(p + 4);
  float v[8] = {a.x, a.y, a.z, a.w, b.x, b.y, b.z, b.w};
  union { short8 s; unsigned short u[8]; } H, L;
#pragma unroll
  for (int i = 0; i < 8; ++i) splitf(v[i], H.u[i], L.u[i]);
  h8 = H.s; l8 = L.s;
}

// Register transpose (verified R5/R6): C-layout tile val(n=lane16, m=mt*16+quad*4+r),
// rows m0/m1 -> split frag F[lane16][k=quad*8+j] over the 32-wide m-window.
DEV void xpose_frag(floatx4 m0, floatx4 m1, int lane16, int quad,
                    short8& hi, short8& lo) {
  union { short8 s; unsigned short u[8]; } H, L;
#pragma unroll
  for (int j = 0; j < 8; ++j) {
    int srcLane = lane16 + (((quad & 1) * 2 + (j >> 2)) << 4);
    float vA = __shfl(m0[j & 3], srcLane, 64);
    float vB = __shfl(m1[j & 3], srcLane, 64);
    float v = (quad < 2) ? vA : vB;
    splitf(v, H.u[j], L.u[j]);
  }
  hi = H.s; lo = L.s;
}

// ---------------- k_prep: Wq/Wk/Wv split-transpose + zero ctx/ksum ----------------
__global__ void k_prep(const float* __restrict__ Wq, const float* __restrict__ Wk,
                       const float* __restrict__ Wv,
                       unsigned short* __restrict__ WTh, unsigned short* __restrict__ WTl,
                       float* __restrict__ ctxz) {
  int gid = blockIdx.x * 256 + threadIdx.x;
  if (gid < 6144) {               // 3 mats x 128 n x 16 k-groups of 8
    int mat = gid >> 11, r = gid & 2047, n = r >> 4, k0 = (r & 15) * 8;
    const float* W = (mat == 0) ? Wq : (mat == 1) ? Wk : Wv;
    union { uint4 q; unsigned short u[8]; } oh, ol;
#pragma unroll
    for (int i = 0; i < 8; ++i) splitf(W[(size_t)(k0 + i) * 128 + n], oh.u[i], ol.u[i]);
    *(uint4*)&WTh[mat * 16384 + n * 128 + k0] = oh.q;
    *(uint4*)&WTl[mat * 16384 + n * 128 + k0] = ol.q;
  } else if (gid < 6144 + 17408) {
    ctxz[gid - 6144] = 0.0f;      // ctx (16384) + ksum (1024)
  }
}

// ---------------- kernel 1: qkv GEMM + rope/elu + q'/ksum/ctx. 512 thr, wave=1 head ----------------
__global__ __launch_bounds__(512) void k_qkv(
    const float* __restrict__ x,
    const unsigned short* __restrict__ WTh, const unsigned short* __restrict__ WTl,
    const float* __restrict__ bq, const float* __restrict__ bk, const float* __restrict__ bv,
    float* __restrict__ ctx, float* __restrict__ ksum,
    unsigned short* __restrict__ qws) {
  __shared__ unsigned short xh[64 * 136], xl[64 * 136];   // pre-split x tile [row][k], pad 8
  __shared__ float rc[64][9], rs[64][9];
  const int tid = threadIdx.x;
  const int row0 = blockIdx.x * 64;
  const int b = row0 >> 13;
  const int t0 = row0 & 8191;

  {  // rope table: 512 threads -> 64 rows x 8 j
    int r = tid >> 3, j = tid & 7;
    float invf = 1.0f / powf(10000.0f, (float)j * 0.125f);
    float s, c;
    sincosf((float)(t0 + r) * invf, &s, &c);
    rc[r][j] = c; rs[r][j] = s;
  }
  {  // stage x, split ONCE per element
    int r = tid >> 3, cg = (tid & 7) * 16;
    const float* xp = x + (size_t)(row0 + r) * 128 + cg;
    short8 h0, l0, h1, l1;
    split8(xp, h0, l0);
    split8(xp + 8, h1, l1);
    *(short8*)&xh[r * 136 + cg] = h0;
    *(short8*)&xh[r * 136 + cg + 8] = h1;
    *(short8*)&xl[r * 136 + cg] = l0;
    *(short8*)&xl[r * 136 + cg + 8] = l1;
  }
  __syncthreads();                 // only barrier

  const int l = tid & 63, w = tid >> 6;       // wave w owns head w
  const int lane16 = l & 15, quad = l >> 4;

  floatx4 acc[3][4];               // [mat: q,k,v][mt]  = 48 AGPRs
#pragma unroll
  for (int i = 0; i < 3; ++i)
#pragma unroll
    for (int j = 0; j < 4; ++j) acc[i][j] = (floatx4){0.f, 0.f, 0.f, 0.f};

#pragma unroll
  for (int ks = 0; ks < 4; ++ks) {
    short8 afh[4], afl[4];
#pragma unroll
    for (int mt = 0; mt < 4; ++mt) {
      int off = (mt * 16 + lane16) * 136 + ks * 32 + quad * 8;
      afh[mt] = *(const short8*)&xh[off];
      afl[mt] = *(const short8*)&xl[off];
    }
#pragma unroll
    for (int mat = 0; mat < 3; ++mat) {
      size_t woff = (size_t)mat * 16384 +
                    (size_t)(w * 16 + lane16) * 128 + ks * 32 + quad * 8;
      short8 bh = *(const short8*)(WTh + woff);
      short8 bl = *(const short8*)(WTl + woff);
#pragma unroll
      for (int mt = 0; mt < 4; ++mt) {
        acc[mat][mt] = MFMA(afh[mt], bh, acc[mat][mt], 0, 0, 0);
        acc[mat][mt] = MFMA(afl[mt], bh, acc[mat][mt], 0, 0, 0);
        acc[mat][mt] = MFMA(afh[mt], bl, acc[mat][mt], 0, 0, 0);
      }
    }
  }

  // bias (lane16 = col within head)
  {
    int col = w * 16 + lane16;
    float bias[3] = {bq[col], bk[col], bv[col]};
#pragma unroll
    for (int mat = 0; mat < 3; ++mat)
#pragma unroll
      for (int mt = 0; mt < 4; ++mt)
#pragma unroll
        for (int r = 0; r < 4; ++r) acc[mat][mt][r] += bias[mat];
  }

  // rope + elu+1 on q (mat 0) and k (mat 1). lane16 = d; t = mt*16 + quad*4 + r.
  {
    const int d = lane16, j = d & 7;
#pragma unroll
    for (int mt = 0; mt < 4; ++mt) {
      float cc[4], ss[4];
#pragma unroll
      for (int r = 0; r < 4; ++r) {
        int tl = mt * 16 + quad * 4 + r;
        cc[r] = rc[tl][j]; ss[r] = rs[tl][j];
      }
#pragma unroll
      for (int mat = 0; mat < 2; ++mat) {
#pragma unroll
        for (int r = 0; r < 4; ++r) {
          float v = acc[mat][mt][r];
          float p = __shfl_xor(v, 8);          // pair (d, d+8)
          float nv = (d < 8) ? (v * cc[r] - p * ss[r]) : (p * ss[r] + v * cc[r]);
          acc[mat][mt][r] = (nv > 0.f) ? (nv + 1.f) : __expf(nv);
        }
      }
    }
  }

  // ksum[h=w][d] from k
  {
    float s = 0.f;
#pragma unroll
    for (int mt = 0; mt < 4; ++mt)
#pragma unroll
      for (int r = 0; r < 4; ++r) s += acc[1][mt][r];
    s += __shfl_xor(s, 16);
    s += __shfl_xor(s, 32);
    if (l < 16) atomicAdd(&ksum[(b * 8 + w) * 16 + lane16], s);
  }

  // q' -> ws bf16 [t][128]
#pragma unroll
  for (int mt = 0; mt < 4; ++mt)
#pragma unroll
    for (int r = 0; r < 4; ++r)
      qws[(size_t)(row0 + mt * 16 + quad * 4 + r) * 128 + w * 16 + lane16] =
          bfh(acc[0][mt][r]);

  // ctx[h=w] += K^T V via register transposes (2 t-windows of 32)
  {
    floatx4 c = (floatx4){0.f, 0.f, 0.f, 0.f};
#pragma unroll
    for (int ks2 = 0; ks2 < 2; ++ks2) {
      short8 kh, kl, vh, vl;
      xpose_frag(acc[1][ks2 * 2], acc[1][ks2 * 2 + 1], lane16, quad, kh, kl);
      xpose_frag(acc[2][ks2 * 2], acc[2][ks2 * 2 + 1], lane16, quad, vh, vl);
      c = MFMA(kh, vh, c, 0, 0, 0);
      c = MFMA(kl, vh, c, 0, 0, 0);
      c = MFMA(kh, vl, c, 0, 0, 0);
    }
#pragma unroll
    for (int r = 0; r < 4; ++r)
      atomicAdd(&ctx[((size_t)(b * 8 + w) * 16 + quad * 4 + r) * 16 + lane16], c[r]);
  }
}

// ---------------- k_mprep: M^T[b][oc][qc] = (C_h @ Wo_h)^T, split bf16 ----------------
__global__ void k_mprep(const float* __restrict__ Wo, const float* __restrict__ ctx,
                        unsigned short* __restrict__ MTh, unsigned short* __restrict__ MTl) {
  int gid = blockIdx.x * 256 + threadIdx.x;   // 64 blocks: 8 b x 128 oc x 16 qc-groups
  int b = gid >> 11, r = gid & 2047, oc = r >> 4, qcg = r & 15;
  int h = qcg >> 1, d0 = (qcg & 1) * 8;
  const float* C = ctx + (size_t)(b * 8 + h) * 256;   // [d][e]
  float m[8] = {0.f, 0.f, 0.f, 0.f, 0.f, 0.f, 0.f, 0.f};
#pragma unroll 4
  for (int e = 0; e < 16; ++e) {
    float wv = Wo[(size_t)(h * 16 + e) * 128 + oc];
#pragma unroll
    for (int i = 0; i < 8; ++i) m[i] += C[(d0 + i) * 16 + e] * wv;
  }
  union { uint4 q; unsigned short u[8]; } oh, ol;
#pragma unroll
  for (int i = 0; i < 8; ++i) splitf(m[i], oh.u[i], ol.u[i]);
  *(uint4*)&MTh[(size_t)gid * 8] = oh.q;     // gid*8 = ((b*128+oc)*16+qcg)*8
  *(uint4*)&MTl[(size_t)gid * 8] = ol.q;
}

// ---------------- kernel 2: out = (z .* q') @ M + bo. 128 rows/block, 32/wave ----------------
__global__ __launch_bounds__(256) void k_zout(
    const unsigned short* __restrict__ qws,
    const unsigned short* __restrict__ MTh, const unsigned short* __restrict__ MTl,
    const float* __restrict__ bo, const float* __restrict__ ksum,
    float* __restrict__ out) {
  __shared__ float ksumS[128], boS[128];
  const int tid = threadIdx.x;
  const int row0 = blockIdx.x * 128;
  const int b = row0 >> 13;

  if (tid < 128) ksumS[tid] = ksum[b * 128 + tid];
  else boS[tid - 128] = bo[tid - 128];
  __syncthreads();                 // only barrier

  const int l = tid & 63, w = tid >> 6;
  const int lane16 = l & 15, quad = l >> 4;
  const unsigned short* MThb = MTh + (size_t)b * 16384;
  const unsigned short* MTlb = MTl + (size_t)b * 16384;

  // A-frags: q' direct from ws (already frag-layout), z in-reg, scale+split
  short8 ah[2][4], al[2][4];
#pragma unroll
  for (int mt2 = 0; mt2 < 2; ++mt2) {
    int trow = row0 + w * 32 + mt2 * 16 + lane16;      // lane16 = t
#pragma unroll
    for (int ks = 0; ks < 4; ++ks) {
      union { short8 s8; unsigned short u[8]; } qq;
      qq.s8 = *(const short8*)&qws[(size_t)trow * 128 + ks * 32 + quad * 8];
      // head of this frag: hq = ks*2 + (quad>>1); within-head d = (quad&1)*8 + j
      int kb = ks * 32 + quad * 8;
      float s = 0.f;
#pragma unroll
      for (int j = 0; j < 8; ++j) s += bfdec(qq.u[j]) * ksumS[kb + j];
      s += __shfl_xor(s, 16);        // combine the two 8-halves of the head
      float z = 1.0f / (s + 1e-6f);
      union { short8 s8; unsigned short u[8]; } H, L;
#pragma unroll
      for (int j = 0; j < 8; ++j) splitf(bfdec(qq.u[j]) * z, H.u[j], L.u[j]);
      ah[mt2][ks] = H.s8;
      al[mt2][ks] = L.s8;
    }
  }

  floatx4 oacc[2][8];
#pragma unroll
  for (int i = 0; i < 2; ++i)
#pragma unroll
    for (int j = 0; j < 8; ++j) oacc[i][j] = (floatx4){0.f, 0.f, 0.f, 0.f};

#pragma unroll
  for (int nt = 0; nt < 8; ++nt) {
#pragma unroll
    for (int ks = 0; ks < 4; ++ks) {
      size_t off = (size_t)(nt * 16 + lane16) * 128 + ks * 32 + quad * 8;
      short8 wbh = *(const short8*)(MThb + off);
      short8 wbl = *(const short8*)(MTlb + off);
#pragma unroll
      for (int mt2 = 0; mt2 < 2; ++mt2) {
        oacc[mt2][nt] = MFMA(ah[mt2][ks], wbh, oacc[mt2][nt], 0, 0, 0);
        oacc[mt2][nt] = MFMA(al[mt2][ks], wbh, oacc[mt2][nt], 0, 0, 0);
        oacc[mt2][nt] = MFMA(ah[mt2][ks], wbl, oacc[mt2][nt], 0, 0, 0);
      }
    }
  }

#pragma unroll
  for (int nt = 0; nt < 8; ++nt) {
    int oc = nt * 16 + lane16;
    float bb = boS[oc];
#pragma unroll
    for (int mt2 = 0; mt2 < 2; ++mt2)
#pragma unroll
      for (int r = 0; r < 4; ++r) {
        int t = row0 + w * 32 + mt2 * 16 + quad * 4 + r;
        out[(size_t)t * 128 + oc] = oacc[mt2][nt][r] + bb;
      }
  }
}

extern "C" void kernel_launch(void* const* d_in, const int* in_sizes, int n_in,
                              void* d_out, int out_size, void* d_ws, size_t ws_size,
                              hipStream_t stream) {
  const float* x  = (const float*)d_in[0];
  const float* Wq = (const float*)d_in[1];
  const float* bq = (const float*)d_in[2];
  const float* Wk = (const float*)d_in[3];
  const float* bk = (const float*)d_in[4];
  const float* Wv = (const float*)d_in[5];
  const float* bv = (const float*)d_in[6];
  const float* Wo = (const float*)d_in[7];
  const float* bo = (const float*)d_in[8];
  float* out = (float*)d_out;

  // ws: qws 16.78MB | WTh 96KB | WTl 96KB | ctx 64KB | ksum 4KB | MTh 256KB | MTl 256KB
  unsigned short* qws = (unsigned short*)d_ws;         // 65536*128 shorts
  unsigned short* WTh = qws + 8388608;                 // 3 x 16384
  unsigned short* WTl = WTh + 49152;
  float* ctx  = (float*)(WTl + 49152);                 // 16384 f
  float* ksum = ctx + 16384;                           // 1024 f
  unsigned short* MTh = (unsigned short*)(ksum + 1024);  // 8 x 16384
  unsigned short* MTl = MTh + 131072;

  k_prep<<<92, 256, 0, stream>>>(Wq, Wk, Wv, WTh, WTl, ctx);
  k_qkv<<<1024, 512, 0, stream>>>(x, WTh, WTl, bq, bk, bv, ctx, ksum, qws);
  k_mprep<<<64, 256, 0, stream>>>(Wo, ctx, MTh, MTl);
  k_zout<<<512, 256, 0, stream>>>(qws, MTh, MTl, bo, ksum, out);
}

// Round 8
// 159.401 us; speedup vs baseline: 1.3117x; 1.0768x over previous
//
#include <hip/hip_runtime.h>
#include <hip/hip_bf16.h>

// LightningAttention MI355X — round 8.
// R7 + (1) k_qkv: double-buffered weight-frag prefetch (loads for ks+1 in flight during ks MFMAs)
//      (2) k_zout: M staged in LDS via global_load_lds, frag-major permuted M layout (conflict-free)
// B=8 T=8192 DM=128 H=8 Dh=16. Split-bf16 (hi+lo) on all MFMA surfaces except q' (bf16).

typedef __attribute__((ext_vector_type(8))) short short8;   // 8 bf16 (MFMA A/B frag)
typedef __attribute__((ext_vector_type(4))) float floatx4;  // MFMA C/D frag

#define DEV __device__ __forceinline__
#define MFMA __builtin_amdgcn_mfma_f32_16x16x32_bf16

DEV unsigned short bfh(float f) {
  unsigned int x = __float_as_uint(f);
  x += 0x7fffu + ((x >> 16) & 1u);     // RNE
  return (unsigned short)(x >> 16);
}
DEV float bfdec(unsigned short u) { return __uint_as_float(((unsigned int)u) << 16); }
DEV void splitf(float f, unsigned short& h, unsigned short& l) {
  h = bfh(f);
  l = bfh(f - bfdec(h));
}
DEV void split8(const float* p, short8& h8, short8& l8) {
  float4 a = *(const float4*)p;
  float4 b = *(const float4*)(p + 4);
  float v[8] = {a.x, a.y, a.z, a.w, b.x, b.y, b.z, b.w};
  union { short8 s; unsigned short u[8]; } H, L;
#pragma unroll
  for (int i = 0; i < 8; ++i) splitf(v[i], H.u[i], L.u[i]);
  h8 = H.s; l8 = L.s;
}

// Register transpose (verified R5-R7): C-layout tile val(n=lane16, m=mt*16+quad*4+r),
// rows m0/m1 -> split frag F[lane16][k=quad*8+j] over the 32-wide m-window.
DEV void xpose_frag(floatx4 m0, floatx4 m1, int lane16, int quad,
                    short8& hi, short8& lo) {
  union { short8 s; unsigned short u[8]; } H, L;
#pragma unroll
  for (int j = 0; j < 8; ++j) {
    int srcLane = lane16 + (((quad & 1) * 2 + (j >> 2)) << 4);
    float vA = __shfl(m0[j & 3], srcLane, 64);
    float vB = __shfl(m1[j & 3], srcLane, 64);
    float v = (quad < 2) ? vA : vB;
    splitf(v, H.u[j], L.u[j]);
  }
  hi = H.s; lo = L.s;
}

// async 16B global->LDS (per-lane gsrc; LDS dest must be wave-uniform base + lane*16)
DEV void async16(const void* g, void* l) {
  __builtin_amdgcn_global_load_lds(
      (const __attribute__((address_space(1))) unsigned int*)g,
      (__attribute__((address_space(3))) unsigned int*)l, 16, 0, 0);
}

// ---------------- k_prep: Wq/Wk/Wv split-transpose + zero ctx/ksum ----------------
__global__ void k_prep(const float* __restrict__ Wq, const float* __restrict__ Wk,
                       const float* __restrict__ Wv,
                       unsigned short* __restrict__ WTh, unsigned short* __restrict__ WTl,
                       float* __restrict__ ctxz) {
  int gid = blockIdx.x * 256 + threadIdx.x;
  if (gid < 6144) {               // 3 mats x 128 n x 16 k-groups of 8
    int mat = gid >> 11, r = gid & 2047, n = r >> 4, k0 = (r & 15) * 8;
    const float* W = (mat == 0) ? Wq : (mat == 1) ? Wk : Wv;
    union { uint4 q; unsigned short u[8]; } oh, ol;
#pragma unroll
    for (int i = 0; i < 8; ++i) splitf(W[(size_t)(k0 + i) * 128 + n], oh.u[i], ol.u[i]);
    *(uint4*)&WTh[mat * 16384 + n * 128 + k0] = oh.q;
    *(uint4*)&WTl[mat * 16384 + n * 128 + k0] = ol.q;
  } else if (gid < 6144 + 17408) {
    ctxz[gid - 6144] = 0.0f;      // ctx (16384) + ksum (1024)
  }
}

// ---------------- kernel 1: qkv GEMM + rope/elu + q'/ksum/ctx. 512 thr, wave=1 head ----------------
__global__ __launch_bounds__(512) void k_qkv(
    const float* __restrict__ x,
    const unsigned short* __restrict__ WTh, const unsigned short* __restrict__ WTl,
    const float* __restrict__ bq, const float* __restrict__ bk, const float* __restrict__ bv,
    float* __restrict__ ctx, float* __restrict__ ksum,
    unsigned short* __restrict__ qws) {
  __shared__ unsigned short xh[64 * 136], xl[64 * 136];   // pre-split x tile [row][k], pad 8
  __shared__ float rc[64][9], rs[64][9];
  const int tid = threadIdx.x;
  const int row0 = blockIdx.x * 64;
  const int b = row0 >> 13;
  const int t0 = row0 & 8191;

  {  // rope table: 512 threads -> 64 rows x 8 j
    int r = tid >> 3, j = tid & 7;
    float invf = 1.0f / powf(10000.0f, (float)j * 0.125f);
    float s, c;
    sincosf((float)(t0 + r) * invf, &s, &c);
    rc[r][j] = c; rs[r][j] = s;
  }
  {  // stage x, split ONCE per element
    int r = tid >> 3, cg = (tid & 7) * 16;
    const float* xp = x + (size_t)(row0 + r) * 128 + cg;
    short8 h0, l0, h1, l1;
    split8(xp, h0, l0);
    split8(xp + 8, h1, l1);
    *(short8*)&xh[r * 136 + cg] = h0;
    *(short8*)&xh[r * 136 + cg + 8] = h1;
    *(short8*)&xl[r * 136 + cg] = l0;
    *(short8*)&xl[r * 136 + cg + 8] = l1;
  }
  __syncthreads();                 // only barrier

  const int l = tid & 63, w = tid >> 6;       // wave w owns head w
  const int lane16 = l & 15, quad = l >> 4;

  floatx4 acc[3][4];               // [mat: q,k,v][mt]  = 48 AGPRs
#pragma unroll
  for (int i = 0; i < 3; ++i)
#pragma unroll
    for (int j = 0; j < 4; ++j) acc[i][j] = (floatx4){0.f, 0.f, 0.f, 0.f};

  // weight base offsets per mat (ks advances by +32 shorts)
  size_t wbase[3];
#pragma unroll
  for (int mat = 0; mat < 3; ++mat)
    wbase[mat] = (size_t)mat * 16384 + (size_t)(w * 16 + lane16) * 128 + quad * 8;

  // double-buffered weight frags: prefetch ks+1 while computing ks
  short8 wh[2][3], wl[2][3];
#pragma unroll
  for (int mat = 0; mat < 3; ++mat) {
    wh[0][mat] = *(const short8*)(WTh + wbase[mat]);
    wl[0][mat] = *(const short8*)(WTl + wbase[mat]);
  }

#pragma unroll
  for (int ks = 0; ks < 4; ++ks) {
    const int cur = ks & 1, nxt = cur ^ 1;
    if (ks < 3) {
#pragma unroll
      for (int mat = 0; mat < 3; ++mat) {
        wh[nxt][mat] = *(const short8*)(WTh + wbase[mat] + (ks + 1) * 32);
        wl[nxt][mat] = *(const short8*)(WTl + wbase[mat] + (ks + 1) * 32);
      }
    }
    short8 afh[4], afl[4];
#pragma unroll
    for (int mt = 0; mt < 4; ++mt) {
      int off = (mt * 16 + lane16) * 136 + ks * 32 + quad * 8;
      afh[mt] = *(const short8*)&xh[off];
      afl[mt] = *(const short8*)&xl[off];
    }
#pragma unroll
    for (int mat = 0; mat < 3; ++mat) {
#pragma unroll
      for (int mt = 0; mt < 4; ++mt) {
        acc[mat][mt] = MFMA(afh[mt], wh[cur][mat], acc[mat][mt], 0, 0, 0);
        acc[mat][mt] = MFMA(afl[mt], wh[cur][mat], acc[mat][mt], 0, 0, 0);
        acc[mat][mt] = MFMA(afh[mt], wl[cur][mat], acc[mat][mt], 0, 0, 0);
      }
    }
  }

  // bias (lane16 = col within head)
  {
    int col = w * 16 + lane16;
    float bias[3] = {bq[col], bk[col], bv[col]};
#pragma unroll
    for (int mat = 0; mat < 3; ++mat)
#pragma unroll
      for (int mt = 0; mt < 4; ++mt)
#pragma unroll
        for (int r = 0; r < 4; ++r) acc[mat][mt][r] += bias[mat];
  }

  // rope + elu+1 on q (mat 0) and k (mat 1). lane16 = d; t = mt*16 + quad*4 + r.
  {
    const int d = lane16, j = d & 7;
#pragma unroll
    for (int mt = 0; mt < 4; ++mt) {
      float cc[4], ss[4];
#pragma unroll
      for (int r = 0; r < 4; ++r) {
        int tl = mt * 16 + quad * 4 + r;
        cc[r] = rc[tl][j]; ss[r] = rs[tl][j];
      }
#pragma unroll
      for (int mat = 0; mat < 2; ++mat) {
#pragma unroll
        for (int r = 0; r < 4; ++r) {
          float v = acc[mat][mt][r];
          float p = __shfl_xor(v, 8);          // pair (d, d+8)
          float nv = (d < 8) ? (v * cc[r] - p * ss[r]) : (p * ss[r] + v * cc[r]);
          acc[mat][mt][r] = (nv > 0.f) ? (nv + 1.f) : __expf(nv);
        }
      }
    }
  }

  // ksum[h=w][d] from k
  {
    float s = 0.f;
#pragma unroll
    for (int mt = 0; mt < 4; ++mt)
#pragma unroll
      for (int r = 0; r < 4; ++r) s += acc[1][mt][r];
    s += __shfl_xor(s, 16);
    s += __shfl_xor(s, 32);
    if (l < 16) atomicAdd(&ksum[(b * 8 + w) * 16 + lane16], s);
  }

  // q' -> ws bf16 [t][128]
#pragma unroll
  for (int mt = 0; mt < 4; ++mt)
#pragma unroll
    for (int r = 0; r < 4; ++r)
      qws[(size_t)(row0 + mt * 16 + quad * 4 + r) * 128 + w * 16 + lane16] =
          bfh(acc[0][mt][r]);

  // ctx[h=w] += K^T V via register transposes (2 t-windows of 32)
  {
    floatx4 c = (floatx4){0.f, 0.f, 0.f, 0.f};
#pragma unroll
    for (int ks2 = 0; ks2 < 2; ++ks2) {
      short8 kh, kl, vh, vl;
      xpose_frag(acc[1][ks2 * 2], acc[1][ks2 * 2 + 1], lane16, quad, kh, kl);
      xpose_frag(acc[2][ks2 * 2], acc[2][ks2 * 2 + 1], lane16, quad, vh, vl);
      c = MFMA(kh, vh, c, 0, 0, 0);
      c = MFMA(kl, vh, c, 0, 0, 0);
      c = MFMA(kh, vl, c, 0, 0, 0);
    }
#pragma unroll
    for (int r = 0; r < 4; ++r)
      atomicAdd(&ctx[((size_t)(b * 8 + w) * 16 + quad * 4 + r) * 16 + lane16], c[r]);
  }
}

// ---------------- k_mprep: M = C_h @ Wo_h (fp32) -> frag-major permuted split-bf16 ----------------
// Consumer frag (nt,ks), lane l reads 16B at group ((nt*4+ks)*64 + l); element j = qc ks*32+(l>>4)*8+j.
__global__ void k_mprep(const float* __restrict__ Wo, const float* __restrict__ ctx,
                        unsigned short* __restrict__ MTh, unsigned short* __restrict__ MTl) {
  int gid = blockIdx.x * 256 + threadIdx.x;   // 64 blocks: 8 b x 128 oc x 16 qc-groups
  int b = gid >> 11, r = gid & 2047, oc = r >> 4, qcg = r & 15;
  int h = qcg >> 1, d0 = (qcg & 1) * 8;
  const float* C = ctx + (size_t)(b * 8 + h) * 256;   // [d][e]
  float m[8] = {0.f, 0.f, 0.f, 0.f, 0.f, 0.f, 0.f, 0.f};
#pragma unroll 4
  for (int e = 0; e < 16; ++e) {
    float wv = Wo[(size_t)(h * 16 + e) * 128 + oc];
#pragma unroll
    for (int i = 0; i < 8; ++i) m[i] += C[(d0 + i) * 16 + e] * wv;
  }
  union { uint4 q; unsigned short u[8]; } oh, ol;
#pragma unroll
  for (int i = 0; i < 8; ++i) splitf(m[i], oh.u[i], ol.u[i]);
  // permuted group index: nt=oc>>4, ks=qcg>>2, l = (qcg&3)*16 + (oc&15)
  int grp = (((oc >> 4) * 4 + (qcg >> 2)) * 64) + (qcg & 3) * 16 + (oc & 15);
  *(uint4*)&MTh[(size_t)b * 16384 + grp * 8] = oh.q;
  *(uint4*)&MTl[(size_t)b * 16384 + grp * 8] = ol.q;
}

// ---------------- kernel 2: out = (z .* q') @ M + bo. M staged in LDS. ----------------
__global__ __launch_bounds__(256) void k_zout(
    const unsigned short* __restrict__ qws,
    const unsigned short* __restrict__ MTh, const unsigned short* __restrict__ MTl,
    const float* __restrict__ bo, const float* __restrict__ ksum,
    float* __restrict__ out) {
  __shared__ __align__(16) unsigned short mh[16384], ml[16384];  // 32KB + 32KB, frag-major
  __shared__ float ksumS[128], boS[128];
  const int tid = threadIdx.x;
  const int row0 = blockIdx.x * 128;
  const int b = row0 >> 13;
  const int l = tid & 63, w = tid >> 6;
  const int lane16 = l & 15, quad = l >> 4;

  {  // async-stage M (this batch's 64KB) into LDS: wave w copies chunks (i*4+w)*1KB
    const char* gh = (const char*)(MTh + (size_t)b * 16384);
    const char* gl = (const char*)(MTl + (size_t)b * 16384);
#pragma unroll
    for (int i = 0; i < 8; ++i) {
      int off = (i * 4 + w) * 1024 + l * 16;
      async16(gh + off, (char*)mh + off);
      async16(gl + off, (char*)ml + off);
    }
  }
  if (tid < 128) ksumS[tid] = ksum[b * 128 + tid];
  else boS[tid - 128] = bo[tid - 128];
  __syncthreads();                 // drains async staging too

  // A-frags: q' direct from ws (already frag-layout), z in-reg, scale+split
  short8 ah[2][4], al[2][4];
#pragma unroll
  for (int mt2 = 0; mt2 < 2; ++mt2) {
    int trow = row0 + w * 32 + mt2 * 16 + lane16;      // lane16 = t
#pragma unroll
    for (int ks = 0; ks < 4; ++ks) {
      union { short8 s8; unsigned short u[8]; } qq;
      qq.s8 = *(const short8*)&qws[(size_t)trow * 128 + ks * 32 + quad * 8];
      int kb = ks * 32 + quad * 8;
      float s = 0.f;
#pragma unroll
      for (int j = 0; j < 8; ++j) s += bfdec(qq.u[j]) * ksumS[kb + j];
      s += __shfl_xor(s, 16);        // combine the two 8-halves of the head
      float z = 1.0f / (s + 1e-6f);
      union { short8 s8; unsigned short u[8]; } H, L;
#pragma unroll
      for (int j = 0; j < 8; ++j) splitf(bfdec(qq.u[j]) * z, H.u[j], L.u[j]);
      ah[mt2][ks] = H.s8;
      al[mt2][ks] = L.s8;
    }
  }

  floatx4 oacc[2][8];
#pragma unroll
  for (int i = 0; i < 2; ++i)
#pragma unroll
    for (int j = 0; j < 8; ++j) oacc[i][j] = (floatx4){0.f, 0.f, 0.f, 0.f};

#pragma unroll
  for (int nt = 0; nt < 8; ++nt) {
#pragma unroll
    for (int ks = 0; ks < 4; ++ks) {
      int moff = ((nt * 4 + ks) * 64 + l) * 8;        // frag-major: lane-contiguous 16B
      short8 wbh = *(const short8*)&mh[moff];
      short8 wbl = *(const short8*)&ml[moff];
#pragma unroll
      for (int mt2 = 0; mt2 < 2; ++mt2) {
        oacc[mt2][nt] = MFMA(ah[mt2][ks], wbh, oacc[mt2][nt], 0, 0, 0);
        oacc[mt2][nt] = MFMA(al[mt2][ks], wbh, oacc[mt2][nt], 0, 0, 0);
        oacc[mt2][nt] = MFMA(ah[mt2][ks], wbl, oacc[mt2][nt], 0, 0, 0);
      }
    }
  }

#pragma unroll
  for (int nt = 0; nt < 8; ++nt) {
    int oc = nt * 16 + lane16;
    float bb = boS[oc];
#pragma unroll
    for (int mt2 = 0; mt2 < 2; ++mt2)
#pragma unroll
      for (int r = 0; r < 4; ++r) {
        int t = row0 + w * 32 + mt2 * 16 + quad * 4 + r;
        out[(size_t)t * 128 + oc] = oacc[mt2][nt][r] + bb;
      }
  }
}

extern "C" void kernel_launch(void* const* d_in, const int* in_sizes, int n_in,
                              void* d_out, int out_size, void* d_ws, size_t ws_size,
                              hipStream_t stream) {
  const float* x  = (const float*)d_in[0];
  const float* Wq = (const float*)d_in[1];
  const float* bq = (const float*)d_in[2];
  const float* Wk = (const float*)d_in[3];
  const float* bk = (const float*)d_in[4];
  const float* Wv = (const float*)d_in[5];
  const float* bv = (const float*)d_in[6];
  const float* Wo = (const float*)d_in[7];
  const float* bo = (const float*)d_in[8];
  float* out = (float*)d_out;

  // ws: qws 16.78MB | WTh 96KB | WTl 96KB | ctx 64KB | ksum 4KB | MTh 256KB | MTl 256KB
  unsigned short* qws = (unsigned short*)d_ws;         // 65536*128 shorts
  unsigned short* WTh = qws + 8388608;                 // 3 x 16384
  unsigned short* WTl = WTh + 49152;
  float* ctx  = (float*)(WTl + 49152);                 // 16384 f
  float* ksum = ctx + 16384;                           // 1024 f
  unsigned short* MTh = (unsigned short*)(ksum + 1024);  // 8 x 16384
  unsigned short* MTl = MTh + 131072;

  k_prep<<<92, 256, 0, stream>>>(Wq, Wk, Wv, WTh, WTl, ctx);
  k_qkv<<<1024, 512, 0, stream>>>(x, WTh, WTl, bq, bk, bv, ctx, ksum, qws);
  k_mprep<<<64, 256, 0, stream>>>(Wo, ctx, MTh, MTl);
  k_zout<<<512, 256, 0, stream>>>(qws, MTh, MTl, bo, ksum, out);
}